// Round 2
// baseline (1317.329 us; speedup 1.0000x reference)
//
#include <hip/hip_runtime.h>

typedef unsigned int uint;
typedef unsigned short ushort;

#define NNODES 100000
#define MP 100096   // 782 * 128
#define NP 100096

typedef __attribute__((ext_vector_type(8))) short bf16x8;
typedef __attribute__((ext_vector_type(4))) float f32x4;

__device__ __forceinline__ float b2f(uint u) {
    union { float f; uint i; } x; x.i = u << 16; return x.f;
}
__device__ __forceinline__ ushort f2b(float f) {
    uint u = __float_as_uint(f);
    u = (u + 0x7fffu + ((u >> 16) & 1u)) >> 16;
    return (ushort)u;
}

// ---------------- graph preprocessing ----------------
// edge_index arrives as int32 (harness converts integer inputs to int): rows = p[0:E], cols = p[E:2E]

__global__ void count_edges(const int* __restrict__ rows, int* __restrict__ cnt, int E) {
    int i = blockIdx.x * 256 + threadIdx.x;
    if (i < E) {
        uint r = (uint)rows[i];
        if (r < NNODES) atomicAdd(&cnt[r], 1);
    }
}

// dinv[i] = rsqrt(cnt[i]+1); row_start via wave-scan + one atomic per wave
__global__ __launch_bounds__(256) void dinv_rowstart(
        const int* __restrict__ cnt, float* __restrict__ dinv,
        int* __restrict__ row_start, int* __restrict__ gcur) {
    int i = blockIdx.x * 256 + threadIdx.x;
    int lane = threadIdx.x & 63;
    int c = (i < NNODES) ? cnt[i] : 0;
    if (i < NNODES) dinv[i] = rsqrtf((float)(c + 1));
    int incl = c;
#pragma unroll
    for (int off = 1; off < 64; off <<= 1) {
        int u = __shfl_up(incl, off, 64);
        if (lane >= off) incl += u;
    }
    int base = 0;
    if (lane == 63) base = atomicAdd(gcur, incl);
    base = __shfl(base, 63, 64);
    if (i < NNODES) row_start[i] = base + incl - c;
}

__global__ void fill_csr(const int* __restrict__ rows, const int* __restrict__ cols,
                         const int* __restrict__ row_start, int* __restrict__ cursor,
                         int* __restrict__ csr_col, int E) {
    int i = blockIdx.x * 256 + threadIdx.x;
    if (i < E) {
        uint r = (uint)rows[i];
        uint c = (uint)cols[i];
        if (r < NNODES && c < NNODES) {
            int slot = atomicAdd(&cursor[r], 1);
            csr_col[row_start[r] + slot] = (int)c;
        }
    }
}

// ---------------- dtype conversion ----------------

__global__ void convert_x(const float* __restrict__ X, ushort* __restrict__ Xb, int n4) {
    int i = blockIdx.x * 256 + threadIdx.x;
    if (i < n4) {
        float4 v = ((const float4*)X)[i];
        uint2 o;
        o.x = (uint)f2b(v.x) | ((uint)f2b(v.y) << 16);
        o.y = (uint)f2b(v.z) | ((uint)f2b(v.w) << 16);
        ((uint2*)Xb)[i] = o;
    }
}

__global__ void transpose_w(const float* __restrict__ W, ushort* __restrict__ Wt, int K, int Nout) {
    int i = blockIdx.x * 256 + threadIdx.x;
    if (i < K * Nout) {
        int k = i / Nout, n = i % Nout;
        Wt[(size_t)n * K + k] = f2b(W[i]);
    }
}

// ---------------- GEMM: C = A (Mp x K) * Bt^T (Bt is Nout x K), bf16 MFMA ----------------
// EPI 0: C[m][n] = dinv[m] * acc  -> bf16 Cb
// EPI 1: C[m][n] = acc + bias[n]  -> fp32 Cf, store only m < Mvalid

template<int KDIM, int NOUT, int EPI>
__global__ __launch_bounds__(256, 2) void gemm_bt(
        const ushort* __restrict__ A, const ushort* __restrict__ Bt,
        ushort* __restrict__ Cb, float* __restrict__ Cf,
        const float* __restrict__ dinv, const float* __restrict__ bias, int Mvalid) {
    __shared__ __align__(16) ushort Alds[128][72];
    __shared__ __align__(16) ushort Blds[128][72];
    __shared__ float dlds[128];

    const int tid = threadIdx.x;
    const int bm0 = blockIdx.x * 128;
    const int bn0 = blockIdx.y * 128;
    const int w = tid >> 6, lane = tid & 63;
    const int wm = (w >> 1) * 64, wn = (w & 1) * 64;
    const int lm = lane & 15, lq = lane >> 4;

    f32x4 acc[4][4] = {};
    if (EPI == 0 && tid < 128) dlds[tid] = dinv[bm0 + tid];

    const int sr = tid >> 3;        // 0..31
    const int sc = (tid & 7) * 8;   // bf16 col 0..56

    for (int k0 = 0; k0 < KDIM; k0 += 64) {
        uint4 ar[4], br[4];
#pragma unroll
        for (int i = 0; i < 4; ++i) {
            int r = sr + i * 32;
            ar[i] = *(const uint4*)&A[(size_t)(bm0 + r) * KDIM + k0 + sc];
            br[i] = *(const uint4*)&Bt[(size_t)(bn0 + r) * KDIM + k0 + sc];
        }
        __syncthreads();
#pragma unroll
        for (int i = 0; i < 4; ++i) {
            int r = sr + i * 32;
            *(uint4*)&Alds[r][sc] = ar[i];
            *(uint4*)&Blds[r][sc] = br[i];
        }
        __syncthreads();
#pragma unroll
        for (int kk = 0; kk < 64; kk += 32) {
            bf16x8 af[4], bfr[4];
#pragma unroll
            for (int t = 0; t < 4; ++t) af[t]  = *(const bf16x8*)&Alds[wm + t * 16 + lm][kk + lq * 8];
#pragma unroll
            for (int t = 0; t < 4; ++t) bfr[t] = *(const bf16x8*)&Blds[wn + t * 16 + lm][kk + lq * 8];
#pragma unroll
            for (int tm = 0; tm < 4; ++tm)
#pragma unroll
                for (int tn = 0; tn < 4; ++tn)
                    acc[tm][tn] = __builtin_amdgcn_mfma_f32_16x16x32_bf16(
                        af[tm], bfr[tn], acc[tm][tn], 0, 0, 0);
        }
    }

    // epilogue: C/D layout col = lane&15, row = (lane>>4)*4 + reg  [m89/m91]
#pragma unroll
    for (int tm = 0; tm < 4; ++tm) {
#pragma unroll
        for (int tn = 0; tn < 4; ++tn) {
#pragma unroll
            for (int r = 0; r < 4; ++r) {
                int lr = wm + tm * 16 + lq * 4 + r;
                int gr = bm0 + lr;
                int gc = bn0 + wn + tn * 16 + lm;
                float v = acc[tm][tn][r];
                if (EPI == 0) {
                    v *= dlds[lr];
                    Cb[(size_t)gr * NOUT + gc] = f2b(v);
                } else {
                    v += bias[gc];
                    if (gr < Mvalid) Cf[(size_t)gr * NOUT + gc] = v;
                }
            }
        }
    }
}

// ---------------- aggregation: out[r] = act(dinv[r]*(sum_{c in N(r)} xw'[c] + xw'[r]) + b) ----------------
// xw' rows are pre-scaled by their own dinv in the GEMM epilogue.
// One wave per row. F=256: 4 bf16/lane; F=128: 2 bf16/lane.

template<int F, bool RELU>
__global__ __launch_bounds__(256) void aggregate(
        const ushort* __restrict__ xw, const int* __restrict__ csr_col,
        const int* __restrict__ row_start, const int* __restrict__ cnt,
        const float* __restrict__ dinv, const float* __restrict__ bias,
        ushort* __restrict__ out) {
    const int row = blockIdx.x * 4 + (threadIdx.x >> 6);
    if (row >= NNODES) return;
    const int lane = threadIdx.x & 63;
    const int s = row_start[row];
    const int e = s + cnt[row];
    const float d = dinv[row];

    if (F == 256) {
        const int f0 = lane * 4;
        uint2 sv = *(const uint2*)(xw + (size_t)row * F + f0);
        float a0 = b2f(sv.x & 0xffffu), a1 = b2f(sv.x >> 16);
        float a2 = b2f(sv.y & 0xffffu), a3 = b2f(sv.y >> 16);
        for (int i = s; i < e; ++i) {
            int c = csr_col[i];
            uint2 v = *(const uint2*)(xw + (size_t)c * F + f0);
            a0 += b2f(v.x & 0xffffu); a1 += b2f(v.x >> 16);
            a2 += b2f(v.y & 0xffffu); a3 += b2f(v.y >> 16);
        }
        float r0 = a0 * d + bias[f0 + 0];
        float r1 = a1 * d + bias[f0 + 1];
        float r2 = a2 * d + bias[f0 + 2];
        float r3 = a3 * d + bias[f0 + 3];
        if (RELU) {
            r0 = fmaxf(r0, 0.f); r1 = fmaxf(r1, 0.f);
            r2 = fmaxf(r2, 0.f); r3 = fmaxf(r3, 0.f);
        }
        uint2 o;
        o.x = (uint)f2b(r0) | ((uint)f2b(r1) << 16);
        o.y = (uint)f2b(r2) | ((uint)f2b(r3) << 16);
        *(uint2*)(out + (size_t)row * F + f0) = o;
    } else {
        const int f0 = lane * 2;
        uint sv = *(const uint*)(xw + (size_t)row * F + f0);
        float a0 = b2f(sv & 0xffffu), a1 = b2f(sv >> 16);
        for (int i = s; i < e; ++i) {
            int c = csr_col[i];
            uint v = *(const uint*)(xw + (size_t)c * F + f0);
            a0 += b2f(v & 0xffffu); a1 += b2f(v >> 16);
        }
        float r0 = a0 * d + bias[f0 + 0];
        float r1 = a1 * d + bias[f0 + 1];
        if (RELU) { r0 = fmaxf(r0, 0.f); r1 = fmaxf(r1, 0.f); }
        *(uint*)(out + (size_t)row * F + f0) = (uint)f2b(r0) | ((uint)f2b(r1) << 16);
    }
}

// ---------------- launch ----------------

extern "C" void kernel_launch(void* const* d_in, const int* in_sizes, int n_in,
                              void* d_out, int out_size, void* d_ws, size_t ws_size,
                              hipStream_t stream) {
    (void)n_in; (void)out_size; (void)ws_size;
    const float* x   = (const float*)d_in[0];
    const int*   ei  = (const int*)d_in[1];   // int64 in reference -> int32 from harness
    const float* W1  = (const float*)d_in[2];
    const float* b1  = (const float*)d_in[3];
    const float* W2  = (const float*)d_in[4];
    const float* b2  = (const float*)d_in[5];
    const float* Wmu = (const float*)d_in[6];
    const float* bmu = (const float*)d_in[7];
    const float* Wlv = (const float*)d_in[8];
    const float* blv = (const float*)d_in[9];
    float* out = (float*)d_out;

    const int E = in_sizes[1] / 2;
    const int* rows = ei;
    const int* cols = ei + E;

    char* ws = (char*)d_ws;
    size_t o = 0;
    int*   cnt       = (int*)(ws + o); o += (size_t)NP * 4;
    int*   cursor    = (int*)(ws + o); o += (size_t)NP * 4;
    int*   gcur      = (int*)(ws + o); o += 256;
    const size_t ZBYTES = o;           // zero cnt + cursor + gcur
    int*   row_start = (int*)(ws + o); o += (size_t)NP * 4;
    float* dinv      = (float*)(ws + o); o += (size_t)NP * 4;
    int*   csr       = (int*)(ws + o); o += (size_t)E * 4;
    ushort* W1t      = (ushort*)(ws + o); o += 256 * 256 * 2;
    ushort* W2t      = (ushort*)(ws + o); o += 256 * 128 * 2;
    ushort* Wmut     = (ushort*)(ws + o); o += 128 * 128 * 2;
    ushort* Wlvt     = (ushort*)(ws + o); o += 128 * 128 * 2;
    o = (o + 4095) & ~(size_t)4095;
    ushort* bufA = (ushort*)(ws + o); o += (size_t)MP * 256 * 2;
    ushort* bufB = (ushort*)(ws + o); o += (size_t)MP * 256 * 2;

    // buffer lifetimes: bufA = xb -> z1 -> z2 ; bufB = xw1 -> xw2
    ushort* xb  = bufA;
    ushort* xw1 = bufB;
    ushort* z1  = bufA;
    ushort* xw2 = bufB;
    ushort* z2  = bufA;

    hipMemsetAsync(d_ws, 0, ZBYTES, stream);

    count_edges<<<dim3((E + 255) / 256), 256, 0, stream>>>(rows, cnt, E);
    dinv_rowstart<<<dim3((NNODES + 255) / 256), 256, 0, stream>>>(cnt, dinv, row_start, gcur);
    fill_csr<<<dim3((E + 255) / 256), 256, 0, stream>>>(rows, cols, row_start, cursor, csr, E);

    convert_x<<<dim3((NNODES * 256 / 4 + 255) / 256), 256, 0, stream>>>(x, xb, NNODES * 256 / 4);
    transpose_w<<<dim3((256 * 256 + 255) / 256), 256, 0, stream>>>(W1, W1t, 256, 256);
    transpose_w<<<dim3((256 * 128 + 255) / 256), 256, 0, stream>>>(W2, W2t, 256, 128);
    transpose_w<<<dim3((128 * 128 + 255) / 256), 256, 0, stream>>>(Wmu, Wmut, 128, 128);
    transpose_w<<<dim3((128 * 128 + 255) / 256), 256, 0, stream>>>(Wlv, Wlvt, 128, 128);

    // conv1: xw1' = dinv .* (x @ W1)   [bf16]
    gemm_bt<256, 256, 0><<<dim3(MP / 128, 2), 256, 0, stream>>>(xb, W1t, xw1, nullptr, dinv, nullptr, MP);
    aggregate<256, true><<<dim3(NNODES / 4), 256, 0, stream>>>(xw1, csr, row_start, cnt, dinv, b1, z1);

    // conv2: xw2' = dinv .* (z1 @ W2)  [bf16]
    gemm_bt<256, 128, 0><<<dim3(MP / 128, 1), 256, 0, stream>>>(z1, W2t, xw2, nullptr, dinv, nullptr, MP);
    aggregate<128, false><<<dim3(NNODES / 4), 256, 0, stream>>>(xw2, csr, row_start, cnt, dinv, b2, z2);

    // heads
    gemm_bt<128, 128, 1><<<dim3(MP / 128, 1), 256, 0, stream>>>(z2, Wmut, nullptr, out, dinv, bmu, NNODES);
    gemm_bt<128, 128, 1><<<dim3(MP / 128, 1), 256, 0, stream>>>(z2, Wlvt, nullptr, out + (size_t)NNODES * 128, dinv, blv, NNODES);
}

// Round 3
// 1007.973 us; speedup vs baseline: 1.3069x; 1.3069x over previous
//
#include <hip/hip_runtime.h>

typedef unsigned int uint;
typedef unsigned short ushort;

#define NNODES 100000
#define MP 100096   // 782 * 128
#define NP 100096

typedef __attribute__((ext_vector_type(8))) short bf16x8;
typedef __attribute__((ext_vector_type(4))) float f32x4;

__device__ __forceinline__ float b2f(uint u) {
    union { float f; uint i; } x; x.i = u << 16; return x.f;
}
__device__ __forceinline__ ushort f2b(float f) {
    uint u = __float_as_uint(f);
    u = (u + 0x7fffu + ((u >> 16) & 1u)) >> 16;
    return (ushort)u;
}

// ---------------- graph preprocessing ----------------
// edge_index arrives as int32 (harness converts integer inputs to int): rows = p[0:E], cols = p[E:2E]

__global__ void count_edges(const int* __restrict__ rows, int* __restrict__ cnt, int E) {
    int i = blockIdx.x * 256 + threadIdx.x;
    if (i < E) {
        uint r = (uint)rows[i];
        if (r < NNODES) atomicAdd(&cnt[r], 1);
    }
}

// dinv[i] = rsqrt(cnt[i]+1); row_start via wave-scan + one atomic per wave
__global__ __launch_bounds__(256) void dinv_rowstart(
        const int* __restrict__ cnt, float* __restrict__ dinv,
        int* __restrict__ row_start, int* __restrict__ gcur) {
    int i = blockIdx.x * 256 + threadIdx.x;
    int lane = threadIdx.x & 63;
    int c = (i < NNODES) ? cnt[i] : 0;
    if (i < NNODES) dinv[i] = rsqrtf((float)(c + 1));
    int incl = c;
#pragma unroll
    for (int off = 1; off < 64; off <<= 1) {
        int u = __shfl_up(incl, off, 64);
        if (lane >= off) incl += u;
    }
    int base = 0;
    if (lane == 63) base = atomicAdd(gcur, incl);
    base = __shfl(base, 63, 64);
    if (i < NNODES) row_start[i] = base + incl - c;
}

__global__ void fill_csr(const int* __restrict__ rows, const int* __restrict__ cols,
                         const int* __restrict__ row_start, int* __restrict__ cursor,
                         int* __restrict__ csr_col, int E) {
    int i = blockIdx.x * 256 + threadIdx.x;
    if (i < E) {
        uint r = (uint)rows[i];
        uint c = (uint)cols[i];
        if (r < NNODES && c < NNODES) {
            int slot = atomicAdd(&cursor[r], 1);
            csr_col[row_start[r] + slot] = (int)c;
        }
    }
}

// ---------------- dtype conversion ----------------

__global__ void convert_x(const float* __restrict__ X, ushort* __restrict__ Xb, int n4) {
    int i = blockIdx.x * 256 + threadIdx.x;
    if (i < n4) {
        float4 v = ((const float4*)X)[i];
        uint2 o;
        o.x = (uint)f2b(v.x) | ((uint)f2b(v.y) << 16);
        o.y = (uint)f2b(v.z) | ((uint)f2b(v.w) << 16);
        ((uint2*)Xb)[i] = o;
    }
}

__global__ void transpose_w(const float* __restrict__ W, ushort* __restrict__ Wt, int K, int Nout) {
    int i = blockIdx.x * 256 + threadIdx.x;
    if (i < K * Nout) {
        int k = i / Nout, n = i % Nout;
        Wt[(size_t)n * K + k] = f2b(W[i]);
    }
}

__global__ void concat_bias(const float* __restrict__ a, const float* __restrict__ b,
                            float* __restrict__ o) {
    int i = threadIdx.x;           // 256 threads
    o[i] = (i < 128) ? a[i] : b[i - 128];
}

// ---------------- GEMM: C = A (Mp x K) * Bt^T (Bt is Nout x K), bf16 MFMA ----------------
// EPI 0: C[m][n] = dinv[m] * acc  -> bf16 Cb
// EPI 1: C[m][n] = acc + bias[n]  -> fp32, split-store: cols 0-127 -> Cf[m][c],
//        cols 128-255 -> Cf[NNODES*128 + m][c-128]; only m < Mvalid

template<int KDIM, int NOUT, int EPI>
__global__ __launch_bounds__(256, 2) void gemm_bt(
        const ushort* __restrict__ A, const ushort* __restrict__ Bt,
        ushort* __restrict__ Cb, float* __restrict__ Cf,
        const float* __restrict__ dinv, const float* __restrict__ bias, int Mvalid) {
    __shared__ __align__(16) ushort Alds[128][72];
    __shared__ __align__(16) ushort Blds[128][72];
    __shared__ float dlds[128];

    const int tid = threadIdx.x;
    const int bm0 = blockIdx.x * 128;
    const int bn0 = blockIdx.y * 128;
    const int w = tid >> 6, lane = tid & 63;
    const int wm = (w >> 1) * 64, wn = (w & 1) * 64;
    const int lm = lane & 15, lq = lane >> 4;

    f32x4 acc[4][4] = {};
    if (EPI == 0 && tid < 128) dlds[tid] = dinv[bm0 + tid];

    const int sr = tid >> 3;        // 0..31
    const int sc = (tid & 7) * 8;   // bf16 col 0..56

    for (int k0 = 0; k0 < KDIM; k0 += 64) {
        uint4 ar[4], br[4];
#pragma unroll
        for (int i = 0; i < 4; ++i) {
            int r = sr + i * 32;
            ar[i] = *(const uint4*)&A[(size_t)(bm0 + r) * KDIM + k0 + sc];
            br[i] = *(const uint4*)&Bt[(size_t)(bn0 + r) * KDIM + k0 + sc];
        }
        __syncthreads();
#pragma unroll
        for (int i = 0; i < 4; ++i) {
            int r = sr + i * 32;
            *(uint4*)&Alds[r][sc] = ar[i];
            *(uint4*)&Blds[r][sc] = br[i];
        }
        __syncthreads();
#pragma unroll
        for (int kk = 0; kk < 64; kk += 32) {
            bf16x8 af[4], bfr[4];
#pragma unroll
            for (int t = 0; t < 4; ++t) af[t]  = *(const bf16x8*)&Alds[wm + t * 16 + lm][kk + lq * 8];
#pragma unroll
            for (int t = 0; t < 4; ++t) bfr[t] = *(const bf16x8*)&Blds[wn + t * 16 + lm][kk + lq * 8];
#pragma unroll
            for (int tm = 0; tm < 4; ++tm)
#pragma unroll
                for (int tn = 0; tn < 4; ++tn)
                    acc[tm][tn] = __builtin_amdgcn_mfma_f32_16x16x32_bf16(
                        af[tm], bfr[tn], acc[tm][tn], 0, 0, 0);
        }
    }

    // epilogue: C/D layout col = lane&15, row = (lane>>4)*4 + reg  [m89/m91]
#pragma unroll
    for (int tm = 0; tm < 4; ++tm) {
#pragma unroll
        for (int tn = 0; tn < 4; ++tn) {
#pragma unroll
            for (int r = 0; r < 4; ++r) {
                int lr = wm + tm * 16 + lq * 4 + r;
                int gr = bm0 + lr;
                int gc = bn0 + wn + tn * 16 + lm;
                float v = acc[tm][tn][r];
                if (EPI == 0) {
                    v *= dlds[lr];
                    Cb[(size_t)gr * NOUT + gc] = f2b(v);
                } else {
                    v += bias[gc];
                    if (gr < Mvalid) {
                        size_t off = (gc < 128)
                            ? ((size_t)gr * 128 + gc)
                            : ((size_t)NNODES * 128 + (size_t)gr * 128 + (gc - 128));
                        Cf[off] = v;
                    }
                }
            }
        }
    }
}

// ---------------- aggregation: out[r] = act(dinv[r]*(sum_{c in N(r)} xw'[c] + xw'[r]) + b) ----------------
// xw' rows are pre-scaled by their own dinv in the GEMM epilogue.
// One wave per row, edge loop unrolled x8 for memory-level parallelism
// (independent gathers issued back-to-back; latency-bound otherwise).

template<int F, bool RELU>
__global__ __launch_bounds__(256) void aggregate(
        const ushort* __restrict__ xw, const int* __restrict__ csr_col,
        const int* __restrict__ row_start, const int* __restrict__ cnt,
        const float* __restrict__ dinv, const float* __restrict__ bias,
        ushort* __restrict__ out) {
    const int row = blockIdx.x * 4 + (threadIdx.x >> 6);
    if (row >= NNODES) return;
    const int lane = threadIdx.x & 63;
    const int s = row_start[row];
    const int e = s + cnt[row];
    const float d = dinv[row];

    if (F == 256) {
        const int f0 = lane * 4;
        const ushort* base = xw + f0;
        uint2 sv = *(const uint2*)(base + (size_t)row * F);
        float a0 = b2f(sv.x & 0xffffu), a1 = b2f(sv.x >> 16);
        float a2 = b2f(sv.y & 0xffffu), a3 = b2f(sv.y >> 16);
        int i = s;
        for (; i + 8 <= e; i += 8) {
            int c[8];
            uint2 v[8];
#pragma unroll
            for (int j = 0; j < 8; ++j) c[j] = csr_col[i + j];
#pragma unroll
            for (int j = 0; j < 8; ++j) v[j] = *(const uint2*)(base + (size_t)c[j] * F);
#pragma unroll
            for (int j = 0; j < 8; ++j) {
                a0 += b2f(v[j].x & 0xffffu); a1 += b2f(v[j].x >> 16);
                a2 += b2f(v[j].y & 0xffffu); a3 += b2f(v[j].y >> 16);
            }
        }
        for (; i < e; ++i) {
            uint2 v = *(const uint2*)(base + (size_t)csr_col[i] * F);
            a0 += b2f(v.x & 0xffffu); a1 += b2f(v.x >> 16);
            a2 += b2f(v.y & 0xffffu); a3 += b2f(v.y >> 16);
        }
        float r0 = a0 * d + bias[f0 + 0];
        float r1 = a1 * d + bias[f0 + 1];
        float r2 = a2 * d + bias[f0 + 2];
        float r3 = a3 * d + bias[f0 + 3];
        if (RELU) {
            r0 = fmaxf(r0, 0.f); r1 = fmaxf(r1, 0.f);
            r2 = fmaxf(r2, 0.f); r3 = fmaxf(r3, 0.f);
        }
        uint2 o;
        o.x = (uint)f2b(r0) | ((uint)f2b(r1) << 16);
        o.y = (uint)f2b(r2) | ((uint)f2b(r3) << 16);
        *(uint2*)(out + (size_t)row * F + f0) = o;
    } else {
        const int f0 = lane * 2;
        const ushort* base = xw + f0;
        uint sv = *(const uint*)(base + (size_t)row * F);
        float a0 = b2f(sv & 0xffffu), a1 = b2f(sv >> 16);
        int i = s;
        for (; i + 8 <= e; i += 8) {
            int c[8];
            uint v[8];
#pragma unroll
            for (int j = 0; j < 8; ++j) c[j] = csr_col[i + j];
#pragma unroll
            for (int j = 0; j < 8; ++j) v[j] = *(const uint*)(base + (size_t)c[j] * F);
#pragma unroll
            for (int j = 0; j < 8; ++j) {
                a0 += b2f(v[j] & 0xffffu); a1 += b2f(v[j] >> 16);
            }
        }
        for (; i < e; ++i) {
            uint v = *(const uint*)(base + (size_t)csr_col[i] * F);
            a0 += b2f(v & 0xffffu); a1 += b2f(v >> 16);
        }
        float r0 = a0 * d + bias[f0 + 0];
        float r1 = a1 * d + bias[f0 + 1];
        if (RELU) { r0 = fmaxf(r0, 0.f); r1 = fmaxf(r1, 0.f); }
        *(uint*)(out + (size_t)row * F + f0) = (uint)f2b(r0) | ((uint)f2b(r1) << 16);
    }
}

// ---------------- launch ----------------

extern "C" void kernel_launch(void* const* d_in, const int* in_sizes, int n_in,
                              void* d_out, int out_size, void* d_ws, size_t ws_size,
                              hipStream_t stream) {
    (void)n_in; (void)out_size; (void)ws_size;
    const float* x   = (const float*)d_in[0];
    const int*   ei  = (const int*)d_in[1];   // int64 in reference -> int32 from harness
    const float* W1  = (const float*)d_in[2];
    const float* b1  = (const float*)d_in[3];
    const float* W2  = (const float*)d_in[4];
    const float* b2  = (const float*)d_in[5];
    const float* Wmu = (const float*)d_in[6];
    const float* bmu = (const float*)d_in[7];
    const float* Wlv = (const float*)d_in[8];
    const float* blv = (const float*)d_in[9];
    float* out = (float*)d_out;

    const int E = in_sizes[1] / 2;
    const int* rows = ei;
    const int* cols = ei + E;

    char* ws = (char*)d_ws;
    size_t o = 0;
    int*   cnt       = (int*)(ws + o); o += (size_t)NP * 4;
    int*   cursor    = (int*)(ws + o); o += (size_t)NP * 4;
    int*   gcur      = (int*)(ws + o); o += 256;
    const size_t ZBYTES = o;           // zero cnt + cursor + gcur
    int*   row_start = (int*)(ws + o); o += (size_t)NP * 4;
    float* dinv      = (float*)(ws + o); o += (size_t)NP * 4;
    float* bcat      = (float*)(ws + o); o += 256 * 4;
    int*   csr       = (int*)(ws + o); o += (size_t)E * 4;
    ushort* W1t      = (ushort*)(ws + o); o += 256 * 256 * 2;
    ushort* W2t      = (ushort*)(ws + o); o += 256 * 128 * 2;
    ushort* Wht      = (ushort*)(ws + o); o += 256 * 128 * 2;  // [Wmu^T ; Wlv^T] rows 0-127 / 128-255
    o = (o + 4095) & ~(size_t)4095;
    ushort* bufA = (ushort*)(ws + o); o += (size_t)MP * 256 * 2;
    ushort* bufB = (ushort*)(ws + o); o += (size_t)MP * 256 * 2;

    // buffer lifetimes: bufA = xb -> z1 -> z2 ; bufB = xw1 -> xw2
    ushort* xb  = bufA;
    ushort* xw1 = bufB;
    ushort* z1  = bufA;
    ushort* xw2 = bufB;
    ushort* z2  = bufA;

    hipMemsetAsync(d_ws, 0, ZBYTES, stream);

    count_edges<<<dim3((E + 255) / 256), 256, 0, stream>>>(rows, cnt, E);
    dinv_rowstart<<<dim3((NNODES + 255) / 256), 256, 0, stream>>>(cnt, dinv, row_start, gcur);
    fill_csr<<<dim3((E + 255) / 256), 256, 0, stream>>>(rows, cols, row_start, cursor, csr, E);

    convert_x<<<dim3((NNODES * 256 / 4 + 255) / 256), 256, 0, stream>>>(x, xb, NNODES * 256 / 4);
    transpose_w<<<dim3((256 * 256 + 255) / 256), 256, 0, stream>>>(W1, W1t, 256, 256);
    transpose_w<<<dim3((256 * 128 + 255) / 256), 256, 0, stream>>>(W2, W2t, 256, 128);
    transpose_w<<<dim3((128 * 128 + 255) / 256), 256, 0, stream>>>(Wmu, Wht, 128, 128);
    transpose_w<<<dim3((128 * 128 + 255) / 256), 256, 0, stream>>>(Wlv, Wht + 128 * 128, 128, 128);
    concat_bias<<<1, 256, 0, stream>>>(bmu, blv, bcat);

    // conv1: xw1' = dinv .* (x @ W1)   [bf16]
    gemm_bt<256, 256, 0><<<dim3(MP / 128, 2), 256, 0, stream>>>(xb, W1t, xw1, nullptr, dinv, nullptr, MP);
    aggregate<256, true><<<dim3(NNODES / 4), 256, 0, stream>>>(xw1, csr, row_start, cnt, dinv, b1, z1);

    // conv2: xw2' = dinv .* (z1 @ W2)  [bf16]
    gemm_bt<256, 128, 0><<<dim3(MP / 128, 1), 256, 0, stream>>>(z1, W2t, xw2, nullptr, dinv, nullptr, MP);
    aggregate<128, false><<<dim3(NNODES / 4), 256, 0, stream>>>(xw2, csr, row_start, cnt, dinv, b2, z2);

    // fused heads: [mu | logvar] = z2 @ [Wmu Wlv] + [bmu blv], split-stored
    gemm_bt<128, 256, 1><<<dim3(MP / 128, 2), 256, 0, stream>>>(z2, Wht, nullptr, out, dinv, bcat, NNODES);
}